// Round 1
// baseline (927.527 us; speedup 1.0000x reference)
//
#include <hip/hip_runtime.h>
#include <stdint.h>

#define T 8192
#define H 1024
#define F 4096
#define E 8
#define K_TOP 2
#define TK (T * K_TOP)

#define BM 128
#define BN 128
#define BK 32

typedef unsigned short u16;
typedef __bf16 bf16x8 __attribute__((ext_vector_type(8)));
typedef float f32x4 __attribute__((ext_vector_type(4)));

// ---------- helpers ----------
__device__ __forceinline__ u16 f2bf(float f) {
    union { float f; uint32_t u; } v; v.f = f;
    uint32_t r = v.u + 0x7FFFu + ((v.u >> 16) & 1u);   // RNE
    return (u16)(r >> 16);
}

__device__ __forceinline__ void async_cp16(const u16* g, u16* l) {
    __builtin_amdgcn_global_load_lds(
        (const __attribute__((address_space(1))) void*)g,
        (__attribute__((address_space(3))) void*)l, 16, 0, 0);
}

// ---------- routing ----------
__global__ __launch_bounds__(256) void count_kernel(const int* __restrict__ ce,
                                                    int* __restrict__ counts) {
    int p = blockIdx.x * 256 + threadIdx.x;
    if (p < TK) atomicAdd(&counts[ce[p]], 1);
}

__global__ void scan_kernel(const int* __restrict__ counts, int* __restrict__ offsets) {
    if (threadIdx.x == 0) {
        int s = 0;
        for (int e = 0; e < E; e++) { offsets[e] = s; s += counts[e]; }
    }
}

__global__ __launch_bounds__(256) void fill_kernel(const int* __restrict__ ce,
                                                   const float* __restrict__ gate,
                                                   const int* __restrict__ offsets,
                                                   int* __restrict__ fill,
                                                   int* __restrict__ tokbuf,
                                                   float* __restrict__ gwbuf) {
    int p = blockIdx.x * 256 + threadIdx.x;
    if (p < TK) {
        int e = ce[p];
        int pos = offsets[e] + atomicAdd(&fill[e], 1);
        tokbuf[pos] = p >> 1;          // t = p / K_TOP (K_TOP==2)
        gwbuf[pos] = gate[p];
    }
}

// ---------- fp32 -> bf16 convert (x) ----------
__global__ __launch_bounds__(256) void cvt_bf16(const float* __restrict__ in,
                                                u16* __restrict__ out, int n) {
    int i = (blockIdx.x * 256 + threadIdx.x) * 4;
    if (i < n) {
        float4 v = *(const float4*)(in + i);
        ushort4 o;
        o.x = f2bf(v.x); o.y = f2bf(v.y); o.z = f2bf(v.z); o.w = f2bf(v.w);
        *(ushort4*)(out + i) = o;
    }
}

// ---------- fp32 (R x C) -> bf16 transposed (C x R), per expert (blockIdx.z) ----------
__global__ __launch_bounds__(256) void transpose_cvt(const float* __restrict__ in,
                                                     u16* __restrict__ out,
                                                     int R, int C) {
    __shared__ u16 tile[64][66];   // +2 pad: column read is 2-way (free)
    int e = blockIdx.z;
    const float* src = in + (size_t)e * R * C;
    u16* dst = out + (size_t)e * R * C;
    int c0 = blockIdx.x * 64, r0 = blockIdx.y * 64;
    int tx = threadIdx.x & 63, ty = threadIdx.x >> 6;
#pragma unroll
    for (int p = 0; p < 16; p++) {
        int row = ty + p * 4;
        tile[row][tx] = f2bf(src[(size_t)(r0 + row) * C + c0 + tx]);
    }
    __syncthreads();
#pragma unroll
    for (int p = 0; p < 16; p++) {
        int row = ty + p * 4;
        dst[(size_t)(c0 + row) * R + r0 + tx] = tile[tx][row];
    }
}

// ---------- fc1: h[slot] = gelu(x[tok[slot]] @ w1[e])  (bf16 out) ----------
__global__ __launch_bounds__(256, 2) void fc1_kernel(const u16* __restrict__ xb,   // T x H
                                                     const u16* __restrict__ w1t,  // E x F x H
                                                     const int* __restrict__ tokbuf,
                                                     const int* __restrict__ counts,
                                                     const int* __restrict__ offsets,
                                                     u16* __restrict__ hbuf) {     // TK x F
    __shared__ __align__(16) u16 As[BM * BK];
    __shared__ __align__(16) u16 Bs[BN * BK];

    const int e = blockIdx.z;
    const int cnt = counts[e];
    const int off = offsets[e];
    const int nt = blockIdx.x;             // F / BN tiles
    const int tid = threadIdx.x;
    const int lane = tid & 63;
    const int wave = tid >> 6;
    const int wr = wave >> 1, wc = wave & 1;
    const int quad = lane >> 4, l16 = lane & 15;
    const int r0 = tid >> 2;               // staging row (0..63)
    const int kc = tid & 3;                // 16B chunk within 64B row

    for (int rt = blockIdx.y; rt * BM < cnt; rt += gridDim.y) {
        int m0 = rt * BM + r0, m1 = m0 + 64;
        int t0 = tokbuf[off + (m0 < cnt ? m0 : cnt - 1)];
        int t1 = tokbuf[off + (m1 < cnt ? m1 : cnt - 1)];
        const u16* a0 = xb + (size_t)t0 * H + kc * 8;
        const u16* a1 = xb + (size_t)t1 * H + kc * 8;
        const u16* b0 = w1t + ((size_t)e * F + nt * BN + r0) * H + kc * 8;
        const u16* b1 = b0 + (size_t)64 * H;

        f32x4 acc[4][4];
#pragma unroll
        for (int i = 0; i < 4; i++)
#pragma unroll
            for (int j = 0; j < 4; j++) acc[i][j] = (f32x4)0.f;

        for (int k0 = 0; k0 < H; k0 += BK) {
            __syncthreads();
            async_cp16(a0 + k0, &As[tid * 8]);
            async_cp16(a1 + k0, &As[(tid + 256) * 8]);
            async_cp16(b0 + k0, &Bs[tid * 8]);
            async_cp16(b1 + k0, &Bs[(tid + 256) * 8]);
            __syncthreads();

            bf16x8 af[4], bfv[4];
#pragma unroll
            for (int mi = 0; mi < 4; mi++)
                af[mi] = *(const bf16x8*)&As[(wr * 64 + mi * 16 + l16) * BK + quad * 8];
#pragma unroll
            for (int ni = 0; ni < 4; ni++)
                bfv[ni] = *(const bf16x8*)&Bs[(wc * 64 + ni * 16 + l16) * BK + quad * 8];
#pragma unroll
            for (int mi = 0; mi < 4; mi++)
#pragma unroll
                for (int ni = 0; ni < 4; ni++)
                    acc[mi][ni] = __builtin_amdgcn_mfma_f32_16x16x32_bf16(
                        af[mi], bfv[ni], acc[mi][ni], 0, 0, 0);
        }

        // epilogue: gelu(tanh approx) -> bf16 h
#pragma unroll
        for (int mi = 0; mi < 4; mi++) {
#pragma unroll
            for (int r = 0; r < 4; r++) {
                int m = rt * BM + wr * 64 + mi * 16 + quad * 4 + r;
                if (m < cnt) {
                    size_t rowbase = (size_t)(off + m) * F;
#pragma unroll
                    for (int ni = 0; ni < 4; ni++) {
                        float v = acc[mi][ni][r];
                        float u = 0.7978845608028654f * (v + 0.044715f * v * v * v);
                        float g = v / (1.f + __expf(-2.f * u));   // v * sigmoid(2u)
                        int fcol = nt * BN + wc * 64 + ni * 16 + l16;
                        hbuf[rowbase + fcol] = f2bf(g);
                    }
                }
            }
        }
    }
}

// ---------- fc2: out[tok[slot]] += gw[slot] * (h[slot] @ w2[e]) ----------
__global__ __launch_bounds__(256, 2) void fc2_kernel(const u16* __restrict__ hbuf,  // TK x F
                                                     const u16* __restrict__ w2t,   // E x H x F
                                                     const int* __restrict__ tokbuf,
                                                     const float* __restrict__ gwbuf,
                                                     const int* __restrict__ counts,
                                                     const int* __restrict__ offsets,
                                                     float* __restrict__ out) {     // T x H
    __shared__ __align__(16) u16 As[BM * BK];
    __shared__ __align__(16) u16 Bs[BN * BK];

    const int e = blockIdx.z;
    const int cnt = counts[e];
    const int off = offsets[e];
    const int nt = blockIdx.x;             // H / BN tiles
    const int tid = threadIdx.x;
    const int lane = tid & 63;
    const int wave = tid >> 6;
    const int wr = wave >> 1, wc = wave & 1;
    const int quad = lane >> 4, l16 = lane & 15;
    const int r0 = tid >> 2;
    const int kc = tid & 3;

    for (int rt = blockIdx.y; rt * BM < cnt; rt += gridDim.y) {
        int m0 = rt * BM + r0, m1 = m0 + 64;
        int s0 = off + (m0 < cnt ? m0 : cnt - 1);
        int s1 = off + (m1 < cnt ? m1 : cnt - 1);
        const u16* a0 = hbuf + (size_t)s0 * F + kc * 8;
        const u16* a1 = hbuf + (size_t)s1 * F + kc * 8;
        const u16* b0 = w2t + ((size_t)e * H + nt * BN + r0) * F + kc * 8;
        const u16* b1 = b0 + (size_t)64 * F;

        f32x4 acc[4][4];
#pragma unroll
        for (int i = 0; i < 4; i++)
#pragma unroll
            for (int j = 0; j < 4; j++) acc[i][j] = (f32x4)0.f;

        for (int k0 = 0; k0 < F; k0 += BK) {
            __syncthreads();
            async_cp16(a0 + k0, &As[tid * 8]);
            async_cp16(a1 + k0, &As[(tid + 256) * 8]);
            async_cp16(b0 + k0, &Bs[tid * 8]);
            async_cp16(b1 + k0, &Bs[(tid + 256) * 8]);
            __syncthreads();

            bf16x8 af[4], bfv[4];
#pragma unroll
            for (int mi = 0; mi < 4; mi++)
                af[mi] = *(const bf16x8*)&As[(wr * 64 + mi * 16 + l16) * BK + quad * 8];
#pragma unroll
            for (int ni = 0; ni < 4; ni++)
                bfv[ni] = *(const bf16x8*)&Bs[(wc * 64 + ni * 16 + l16) * BK + quad * 8];
#pragma unroll
            for (int mi = 0; mi < 4; mi++)
#pragma unroll
                for (int ni = 0; ni < 4; ni++)
                    acc[mi][ni] = __builtin_amdgcn_mfma_f32_16x16x32_bf16(
                        af[mi], bfv[ni], acc[mi][ni], 0, 0, 0);
        }

#pragma unroll
        for (int mi = 0; mi < 4; mi++) {
#pragma unroll
            for (int r = 0; r < 4; r++) {
                int m = rt * BM + wr * 64 + mi * 16 + quad * 4 + r;
                if (m < cnt) {
                    int t = tokbuf[off + m];
                    float g = gwbuf[off + m];
                    size_t obase = (size_t)t * H;
#pragma unroll
                    for (int ni = 0; ni < 4; ni++) {
                        int col = nt * BN + wc * 64 + ni * 16 + l16;
                        atomicAdd(&out[obase + col], g * acc[mi][ni][r]);
                    }
                }
            }
        }
    }
}

// ---------- launch ----------
extern "C" void kernel_launch(void* const* d_in, const int* in_sizes, int n_in,
                              void* d_out, int out_size, void* d_ws, size_t ws_size,
                              hipStream_t stream) {
    const float* x    = (const float*)d_in[0];   // S,B,H fp32
    const float* gate = (const float*)d_in[1];   // T,K
    const int*   ce   = (const int*)d_in[2];     // T,K
    const float* w1   = (const float*)d_in[3];   // E,H,F
    const float* w2   = (const float*)d_in[4];   // E,F,H
    float* out = (float*)d_out;
    char* ws = (char*)d_ws;

    // workspace layout
    int*   counts  = (int*)(ws + 0);                 // 8
    int*   fill    = (int*)(ws + 32);                // 8
    int*   offsets = (int*)(ws + 64);                // 8
    int*   tokbuf  = (int*)(ws + 256);               // TK
    float* gwbuf   = (float*)(ws + 256 + TK * 4);    // TK
    size_t o = 256 + (size_t)TK * 8;
    u16* xb  = (u16*)(ws + o);  o += (size_t)T * H * 2;       // 16.8 MB
    u16* w1t = (u16*)(ws + o);  o += (size_t)E * F * H * 2;   // 67 MB  (E,F,H)
    u16* w2t = (u16*)(ws + o);  o += (size_t)E * H * F * 2;   // 67 MB  (E,H,F)
    u16* hbuf = (u16*)(ws + o);                                // TK x F bf16, 134 MB

    hipMemsetAsync(ws, 0, 256, stream);                        // counts + fill
    hipMemsetAsync(d_out, 0, (size_t)T * H * sizeof(float), stream);

    count_kernel<<<TK / 256, 256, 0, stream>>>(ce, counts);
    scan_kernel<<<1, 64, 0, stream>>>(counts, offsets);
    fill_kernel<<<TK / 256, 256, 0, stream>>>(ce, gate, offsets, fill, tokbuf, gwbuf);

    cvt_bf16<<<(T * H) / (256 * 4), 256, 0, stream>>>(x, xb, T * H);
    transpose_cvt<<<dim3(F / 64, H / 64, E), 256, 0, stream>>>(w1, w1t, H, F);  // (H,F)->(F,H)
    transpose_cvt<<<dim3(H / 64, F / 64, E), 256, 0, stream>>>(w2, w2t, F, H);  // (F,H)->(H,F)

    fc1_kernel<<<dim3(F / BN, 32, E), 256, 0, stream>>>(xb, w1t, tokbuf, counts, offsets, hbuf);
    fc2_kernel<<<dim3(H / BN, 32, E), 256, 0, stream>>>(hbuf, w2t, tokbuf, gwbuf, counts, offsets, out);
}